// Round 1
// 266.501 us; speedup vs baseline: 1.0987x; 1.0987x over previous
//
#include <hip/hip_runtime.h>

// SyntacticGCN on MI355X — fp32 in/out.
// v2: aggregate-then-transform. Since agg[n] = sum_e g_e*(x[src]@W_t) and
// biases are zero on the fast path, swap the linear ops:
//   S[n, t*128+d] = sum_{e:tgt=n,t_e=t} g_e * x[src_e, d]   (gather from 25.6MB xb)
//   out[n] = relu(inp[n] + S[n,:] @ Wcat)                    (one K=512 GEMM)
// This kills the 102.4MB xv intermediate (write + gathered re-read) entirely.
//
// Pipeline (6 dispatches):
//   memset (counts + bnz = 0)
//   conv_hist_k      : [node blocks] inp fp32 -> xb bf16 + gate logits xg
//                      [edge blocks] per-target degree histogram
//                      [sampler blocks] b_in/b_out nonzero check -> bnz
//                      [wconv blocks] W_{in,out,self,norel} fp32 -> wcatT[c][k] bf16
//   scan_block_k     : per-1024-chunk exclusive scan + blocksums
//   scan_add_k       : inline blocksum-prefix + add -> row_start, cursor
//   scatter_payload_k: CSR scatter fused with gate-logit+sigmoid precompute
//   fused_agg_gemm_k : 512 thr / 64-node tile. Phase 1: CSR gather of gated
//                      xb rows into per-branch accumulators (depth-4 gather
//                      pipeline, 2 nodes/wave) -> bf16 S-tile in LDS
//                      (64x512, XOR-swizzled byte^=(row&7)<<4 -> 2-way = free).
//                      Phase 2: S_tile @ Wcat via 16x16x32 bf16 MFMA, weights
//                      64 VGPR/wave (index math copied from proven gemm_xv_k),
//                      + xb residual + relu -> out. Bias (!bz) path exact via
//                      global fp32 Sb side-buffer.

typedef __attribute__((ext_vector_type(8))) short short8;
typedef __attribute__((ext_vector_type(4))) float floatx4;

#define DIM 128

static __device__ __forceinline__ float bf2f(unsigned int u16bits) {
    unsigned int x = u16bits << 16;
    return __builtin_bit_cast(float, x);
}
static __device__ __forceinline__ unsigned int f2bf(float f) {
    unsigned int x = __builtin_bit_cast(unsigned int, f);
    return (x + 0x7fffu + ((x >> 16) & 1u)) >> 16;
}

// ------- fused: conv+gate (node blocks) | hist | zcheck | weight-convert ---------
__global__ __launch_bounds__(256) void conv_hist_k(
    const float* __restrict__ inp,
    const float* __restrict__ gin,  const float* __restrict__ gout,
    const float* __restrict__ gself, const float* __restrict__ gnorel,
    const float* __restrict__ Vin, const float* __restrict__ Vout,
    const float* __restrict__ Wself, const float* __restrict__ Wnorel,
    unsigned short* __restrict__ xb, float* __restrict__ xg,
    unsigned short* __restrict__ wcatT,
    const int* __restrict__ ei, int* __restrict__ counts,
    const float* __restrict__ b_in, const float* __restrict__ b_out,
    int* __restrict__ bnz, long long nbe,
    int N, int E, int nb_conv, int nb_edge)
{
    int bx = (int)blockIdx.x;
    if (bx >= nb_conv + nb_edge + 256) {
        // weight convert: wcatT[c][k] = bf16(W_t[d][c]), k = t*128+d. 128 blocks.
        int gid = (bx - nb_conv - nb_edge - 256) * 256 + threadIdx.x; // 32768
        int k = gid >> 6;            // 0..511
        int c2 = (gid & 63) * 2;     // 0,2,..,126
        int t = k >> 7, d = k & 127;
        const float* Wt = (t == 0) ? Vin : (t == 1) ? Vout : (t == 2) ? Wself : Wnorel;
        float2 w = *(const float2*)(Wt + (size_t)d * DIM + c2);
        wcatT[(size_t)c2 * 512 + k]       = (unsigned short)f2bf(w.x);
        wcatT[(size_t)(c2 + 1) * 512 + k] = (unsigned short)f2bf(w.y);
        return;
    }
    if (bx >= nb_conv + nb_edge) {
        // sampler: 256 blocks x 256 threads, strided over the bias tables
        long long tid = (long long)(bx - nb_conv - nb_edge) * 256 + threadIdx.x;
        long long stride = nbe / 65536;
        long long i = tid * stride;
        if (i < nbe && (b_in[i] != 0.f || b_out[i] != 0.f)) *bnz = 1;
        return;
    }
    if (bx >= nb_conv) {
        int e = (bx - nb_conv) * 256 + threadIdx.x;
        if (e < E) atomicAdd(&counts[ei[E + e]], 1);
        return;
    }
    int n = bx * 4 + (threadIdx.x >> 6);
    if (n >= N) return;
    int lane = threadIdx.x & 63;

    float2 x = *(const float2*)(inp + (size_t)n * DIM + lane * 2);
    unsigned int o = f2bf(x.x) | (f2bf(x.y) << 16);
    *(unsigned int*)(xb + (size_t)n * DIM + lane * 2) = o;

    float2 g0 = *(const float2*)(gin    + lane * 2);
    float2 g1 = *(const float2*)(gout   + lane * 2);
    float2 g2 = *(const float2*)(gself  + lane * 2);
    float2 g3 = *(const float2*)(gnorel + lane * 2);
    float s0 = x.x * g0.x + x.y * g0.y;
    float s1 = x.x * g1.x + x.y * g1.y;
    float s2 = x.x * g2.x + x.y * g2.y;
    float s3 = x.x * g3.x + x.y * g3.y;
#pragma unroll
    for (int off = 1; off < 64; off <<= 1) {
        s0 += __shfl_xor(s0, off, 64);
        s1 += __shfl_xor(s1, off, 64);
        s2 += __shfl_xor(s2, off, 64);
        s3 += __shfl_xor(s3, off, 64);
    }
    if (lane == 0) *(float4*)(xg + (size_t)n * 4) = make_float4(s0, s1, s2, s3);
}

// ---------------- CSR scan (2 kernels, unchanged) ----------------
__global__ __launch_bounds__(256) void scan_block_k(
    const int* __restrict__ counts, int* __restrict__ row_start,
    int* __restrict__ blocksums, int n)
{
    __shared__ int sdata[256];
    int tid = threadIdx.x;
    int base = blockIdx.x * 1024 + tid * 4;
    int v[4]; int s = 0;
#pragma unroll
    for (int j = 0; j < 4; ++j) {
        v[j] = (base + j < n) ? counts[base + j] : 0;
        s += v[j];
    }
    sdata[tid] = s;
    __syncthreads();
    for (int off = 1; off < 256; off <<= 1) {
        int t = (tid >= off) ? sdata[tid - off] : 0;
        __syncthreads();
        sdata[tid] += t;
        __syncthreads();
    }
    int run = sdata[tid] - s;
#pragma unroll
    for (int j = 0; j < 4; ++j) {
        if (base + j < n) row_start[base + j] = run;
        run += v[j];
    }
    if (tid == 255) blocksums[blockIdx.x] = sdata[255];
}

__global__ __launch_bounds__(256) void scan_add_k(
    int* __restrict__ row_start, int* __restrict__ cursor,
    const int* __restrict__ blocksums, int n, int nb)
{
    __shared__ int red[2];
    int tid = threadIdx.x;
    if (tid < 128) {
        int v = (tid < (int)blockIdx.x && tid < nb) ? blocksums[tid] : 0;
#pragma unroll
        for (int o = 1; o < 64; o <<= 1) v += __shfl_xor(v, o, 64);
        if ((tid & 63) == 0) red[tid >> 6] = v;
    }
    __syncthreads();
    int off = red[0] + red[1];

    int base = blockIdx.x * 1024 + tid * 4;
#pragma unroll
    for (int j = 0; j < 4; ++j) {
        int idx = base + j;
        if (idx < n) {
            int v = row_start[idx] + off;
            row_start[idx] = v;
            cursor[idx] = v;
        }
    }
}

// ---------------- fused scatter + gate logit + sigmoid (unchanged) ---------------
__global__ void scatter_payload_k(
    const int* __restrict__ ei, const int* __restrict__ deprel,
    const int* __restrict__ deparc, int* __restrict__ cursor,
    const float* __restrict__ xg,
    const float* __restrict__ bg_in, const float* __restrict__ bg_out,
    int2* __restrict__ pe, float* __restrict__ gate, int E)
{
    int e = blockIdx.x * 256 + threadIdx.x;
    if (e >= E) return;
    int tgt = ei[E + e];
    int src = ei[e];
    int t   = deparc[e];
    int rel = deprel[e];
    int pos = atomicAdd(&cursor[tgt], 1);
    float gl = xg[(size_t)src * 4 + t];
    if (t == 0)      gl += bg_in[rel];
    else if (t == 1) gl += bg_out[rel];
    pe[pos]   = make_int2(src | (t << 20), rel);
    gate[pos] = 1.f / (1.f + __expf(-gl));
}

// ---------------- fused aggregate(S) + GEMM(K=512) + residual + relu -------------
#define XB_GATHER(idx)                                                              \
    ({ int p_ = __shfl(mpx, sl0 + (idx), 64);                                       \
       *(const uint2*)(xb + (size_t)(p_ & 0xFFFFF) * DIM + l * 4); })

#define CONSUME(v, jj) do {                                                         \
    int p_ = __shfl(mpx, sl0 + (jj), 64);                                           \
    float g_ = __shfl(mg, sl0 + (jj), 64);                                          \
    int t_ = (int)((unsigned)p_ >> 20);                                             \
    float x0_ = bf2f((v).x & 0xffffu) * g_;                                         \
    float x1_ = bf2f((v).x >> 16)     * g_;                                         \
    float x2_ = bf2f((v).y & 0xffffu) * g_;                                         \
    float x3_ = bf2f((v).y >> 16)     * g_;                                         \
    if (t_ == 0)      { a00 += x0_; a01 += x1_; a02 += x2_; a03 += x3_; }           \
    else if (t_ == 1) { a10 += x0_; a11 += x1_; a12 += x2_; a13 += x3_; }           \
    else if (t_ == 2) { a20 += x0_; a21 += x1_; a22 += x2_; a23 += x3_; }           \
    else              { a30 += x0_; a31 += x1_; a32 += x2_; a33 += x3_; }           \
} while (0)

__global__ __launch_bounds__(512, 2) void fused_agg_gemm_k(
    const unsigned short* __restrict__ xb,
    const unsigned short* __restrict__ wcatT,
    const int2* __restrict__ pe, const float* __restrict__ gate,
    const int* __restrict__ row_start, const int* __restrict__ counts,
    const float* __restrict__ b_in, const float* __restrict__ b_out,
    float* __restrict__ Sb, float* __restrict__ out,
    const int* __restrict__ bnz, int N)
{
    // S-tile: 64 rows x 512 k, bf16, row stride 1024 B, XOR-swizzled.
    __shared__ __align__(16) unsigned char smem[64 * 1024];

    int tid  = threadIdx.x;
    int wave = tid >> 6, lane = tid & 63;
    int half = lane >> 5, l = lane & 31;
    int rowb = blockIdx.x * 64;
    int bz = (*bnz == 0);

    // ---------------- phase 1: gather-aggregate S into LDS ----------------
    for (int pass = 0; pass < 4; ++pass) {
        int r = pass * 16 + wave * 2 + half;   // row in tile 0..63
        int n = rowb + r;
        bool valid = n < N;
        int start = 0, cnt = 0;
        if (valid) { start = row_start[n]; cnt = counts[n]; }

        float a00 = 0.f, a01 = 0.f, a02 = 0.f, a03 = 0.f;
        float a10 = 0.f, a11 = 0.f, a12 = 0.f, a13 = 0.f;
        float a20 = 0.f, a21 = 0.f, a22 = 0.f, a23 = 0.f;
        float a30 = 0.f, a31 = 0.f, a32 = 0.f, a33 = 0.f;
        float ab0 = 0.f, ab1 = 0.f, ab2 = 0.f, ab3 = 0.f;

        if (bz) {
            // fast path: depth-4 gather pipeline (structure from proven aggregate_k)
            for (int base2 = 0; base2 < cnt; base2 += 32) {
                int m = min(cnt - base2, 32);
                int mpx = 0; float mg = 0.f;
                if (l < m) {
                    mpx = pe[start + base2 + l].x;
                    mg  = gate[start + base2 + l];
                }
                int sl0 = half * 32;

                uint2 v0 = make_uint2(0, 0), v1 = v0, v2 = v0, v3 = v0;
                if (0 < m) v0 = XB_GATHER(0);
                if (1 < m) v1 = XB_GATHER(1);
                if (2 < m) v2 = XB_GATHER(2);
                if (3 < m) v3 = XB_GATHER(3);

                for (int j = 0; j < m; j += 4) {
                    CONSUME(v0, j);
                    if (j + 4 < m) v0 = XB_GATHER(j + 4);
                    if (j + 1 < m) {
                        CONSUME(v1, j + 1);
                        if (j + 5 < m) v1 = XB_GATHER(j + 5);
                    }
                    if (j + 2 < m) {
                        CONSUME(v2, j + 2);
                        if (j + 6 < m) v2 = XB_GATHER(j + 6);
                    }
                    if (j + 3 < m) {
                        CONSUME(v3, j + 3);
                        if (j + 7 < m) v3 = XB_GATHER(j + 7);
                    }
                }
            }
        } else {
            // exact generic path: also accumulate gathered bias rows (output space)
            for (int base2 = 0; base2 < cnt; base2 += 32) {
                int m = min(cnt - base2, 32);
                int mpx = 0, mrl = 0; float mg = 0.f;
                if (l < m) {
                    int2 p = pe[start + base2 + l];
                    mpx = p.x; mrl = p.y;
                    mg  = gate[start + base2 + l];
                }
                int sl0 = half * 32;
                for (int j = 0; j < m; ++j) {
                    int p_ = __shfl(mpx, sl0 + j, 64);
                    float g_ = __shfl(mg, sl0 + j, 64);
                    int rl_ = __shfl(mrl, sl0 + j, 64);
                    int t_ = (int)((unsigned)p_ >> 20);
                    uint2 v = *(const uint2*)(xb + (size_t)(p_ & 0xFFFFF) * DIM + l * 4);
                    float x0_ = bf2f(v.x & 0xffffu) * g_;
                    float x1_ = bf2f(v.x >> 16)     * g_;
                    float x2_ = bf2f(v.y & 0xffffu) * g_;
                    float x3_ = bf2f(v.y >> 16)     * g_;
                    if (t_ == 0)      { a00 += x0_; a01 += x1_; a02 += x2_; a03 += x3_; }
                    else if (t_ == 1) { a10 += x0_; a11 += x1_; a12 += x2_; a13 += x3_; }
                    else if (t_ == 2) { a20 += x0_; a21 += x1_; a22 += x2_; a23 += x3_; }
                    else              { a30 += x0_; a31 += x1_; a32 += x2_; a33 += x3_; }
                    if (t_ < 2) {
                        const float* bt = (t_ == 0) ? b_in : b_out;
                        float4 bb = *(const float4*)(bt + (size_t)rl_ * DIM + l * 4);
                        ab0 += g_ * bb.x; ab1 += g_ * bb.y;
                        ab2 += g_ * bb.z; ab3 += g_ * bb.w;
                    }
                }
            }
        }

        if (valid) {
            // S row layout: k = t*128 + d; lane l covers d = 4l..4l+3 per branch.
            // swizzle: byteoff ^= (row&7)<<4  (2-way bank aliasing max = free)
            unsigned sw = (unsigned)((r & 7) << 4);
            unsigned rb = (unsigned)r * 1024;
            *(uint2*)(&smem[rb + ((  0u + l * 8u) ^ sw)]) =
                make_uint2(f2bf(a00) | (f2bf(a01) << 16), f2bf(a02) | (f2bf(a03) << 16));
            *(uint2*)(&smem[rb + ((256u + l * 8u) ^ sw)]) =
                make_uint2(f2bf(a10) | (f2bf(a11) << 16), f2bf(a12) | (f2bf(a13) << 16));
            *(uint2*)(&smem[rb + ((512u + l * 8u) ^ sw)]) =
                make_uint2(f2bf(a20) | (f2bf(a21) << 16), f2bf(a22) | (f2bf(a23) << 16));
            *(uint2*)(&smem[rb + ((768u + l * 8u) ^ sw)]) =
                make_uint2(f2bf(a30) | (f2bf(a31) << 16), f2bf(a32) | (f2bf(a33) << 16));
            if (!bz)
                *(float4*)(Sb + (size_t)n * DIM + l * 4) =
                    make_float4(ab0, ab1, ab2, ab3);
        }
    }

    // weight fragments issued before the barrier so the loads overlap it.
    // A-operand layout copied from gemm_xv_k: col = cb on lane&15, k = quad*8+j.
    int quad = lane >> 4, l15 = lane & 15;
    int colb = wave * 16 + quad * 4;
    const unsigned short* wc = wcatT + (size_t)(wave * 16 + l15) * 512;
    short8 wf[16];
#pragma unroll
    for (int kt = 0; kt < 16; ++kt)
        wf[kt] = *(const short8*)(wc + kt * 32 + quad * 8);

    __syncthreads();

    // ---------------- phase 2: S_tile @ Wcat (K=512) ----------------
    floatx4 ac0 = {0.f, 0.f, 0.f, 0.f}, ac1 = ac0, ac2 = ac0, ac3 = ac0;
    unsigned swl = (unsigned)((l15 & 7) << 4);
#pragma unroll
    for (int kt = 0; kt < 16; ++kt) {
        unsigned bo = ((unsigned)(kt * 64 + quad * 16)) ^ swl;
        short8 x0 = *(const short8*)(&smem[(unsigned)(     l15) * 1024 + bo]);
        short8 x1 = *(const short8*)(&smem[(unsigned)(16 + l15) * 1024 + bo]);
        short8 x2 = *(const short8*)(&smem[(unsigned)(32 + l15) * 1024 + bo]);
        short8 x3 = *(const short8*)(&smem[(unsigned)(48 + l15) * 1024 + bo]);
        ac0 = __builtin_amdgcn_mfma_f32_16x16x32_bf16(wf[kt], x0, ac0, 0, 0, 0);
        ac1 = __builtin_amdgcn_mfma_f32_16x16x32_bf16(wf[kt], x1, ac1, 0, 0, 0);
        ac2 = __builtin_amdgcn_mfma_f32_16x16x32_bf16(wf[kt], x2, ac2, 0, 0, 0);
        ac3 = __builtin_amdgcn_mfma_f32_16x16x32_bf16(wf[kt], x3, ac3, 0, 0, 0);
    }

    // epilogue: + xb residual (+ Sb bias term if !bz), relu, store.
    // D layout (from gemm_xv_k): row = l15 (+16*s), col = colb + reg.
#define EPI(AC, S) do {                                                             \
    int row = rowb + (S) * 16 + l15;                                                \
    if (row < N) {                                                                  \
        uint2 ix = *(const uint2*)(xb + (size_t)row * DIM + colb);                  \
        float4 o;                                                                   \
        o.x = (AC)[0] + bf2f(ix.x & 0xffffu);                                       \
        o.y = (AC)[1] + bf2f(ix.x >> 16);                                           \
        o.z = (AC)[2] + bf2f(ix.y & 0xffffu);                                       \
        o.w = (AC)[3] + bf2f(ix.y >> 16);                                           \
        if (!bz) {                                                                  \
            float4 sb = *(const float4*)(Sb + (size_t)row * DIM + colb);            \
            o.x += sb.x; o.y += sb.y; o.z += sb.z; o.w += sb.w;                     \
        }                                                                           \
        o.x = fmaxf(o.x, 0.f); o.y = fmaxf(o.y, 0.f);                               \
        o.z = fmaxf(o.z, 0.f); o.w = fmaxf(o.w, 0.f);                               \
        *(float4*)(out + (size_t)row * DIM + colb) = o;                             \
    }                                                                               \
} while (0)

    EPI(ac0, 0);
    EPI(ac1, 1);
    EPI(ac2, 2);
    EPI(ac3, 3);
#undef EPI
}

extern "C" void kernel_launch(void* const* d_in, const int* in_sizes, int n_in,
                              void* d_out, int out_size, void* d_ws, size_t ws_size,
                              hipStream_t stream)
{
    const float* inp    = (const float*)d_in[0];
    const int*   deprel = (const int*)d_in[1];
    const int*   deparc = (const int*)d_in[2];
    const int*   ei     = (const int*)d_in[3];
    const float* Vin    = (const float*)d_in[4];
    const float* b_in   = (const float*)d_in[5];
    const float* gin    = (const float*)d_in[6];
    const float* bg_in  = (const float*)d_in[7];
    const float* Vout   = (const float*)d_in[8];
    const float* b_out  = (const float*)d_in[9];
    const float* gout   = (const float*)d_in[10];
    const float* bg_out = (const float*)d_in[11];
    const float* Wself  = (const float*)d_in[12];
    const float* gself  = (const float*)d_in[13];
    const float* Wnorel = (const float*)d_in[14];
    const float* gnorel = (const float*)d_in[15];
    float*       out    = (float*)d_out;

    const int N = in_sizes[0] / DIM;   // 100000
    const int E = in_sizes[1];         // 400000
    const long long nbe = (long long)in_sizes[5];  // R*128

    char* ws = (char*)d_ws;
    size_t off = 0;
    auto alloc = [&](size_t bytes) -> void* {
        void* p = ws + off;
        off = (off + bytes + 255) & ~(size_t)255;
        return p;
    };
    float*          xg        = (float*)alloc((size_t)N * 4 * 4);
    int*            counts    = (int*)alloc((size_t)N * 4);   // |
    int*            bnz       = (int*)alloc(256);             // | one memset region
    int*            row_start = (int*)alloc((size_t)N * 4);
    int*            cursor    = (int*)alloc((size_t)N * 4);
    int2*           pe        = (int2*)alloc((size_t)E * 8);
    float*          gate      = (float*)alloc((size_t)E * 4);
    int*            blocksums = (int*)alloc(128 * 4);
    unsigned short* xb        = (unsigned short*)alloc((size_t)N * DIM * 2); // 25.6 MB
    unsigned short* wcatT     = (unsigned short*)alloc((size_t)128 * 512 * 2); // 128 KB
    float*          Sb        = (float*)alloc((size_t)N * DIM * 4);          // 51.2 MB

    int nb_scan  = (N + 1023) / 1024;
    int nb_edge  = (E + 255) / 256;
    int nb_node4 = (N + 3) / 4;
    int nb_fused = (N + 63) / 64;

    // zero counts + bnz in one memset (adjacent in ws)
    size_t zlen = (size_t)((char*)bnz - (char*)counts) + 256;
    hipMemsetAsync(counts, 0, zlen, stream);

    conv_hist_k<<<nb_node4 + nb_edge + 256 + 128, 256, 0, stream>>>(
        inp, gin, gout, gself, gnorel, Vin, Vout, Wself, Wnorel,
        xb, xg, wcatT, ei, counts, b_in, b_out, bnz, nbe, N, E, nb_node4, nb_edge);

    scan_block_k<<<nb_scan, 256, 0, stream>>>(counts, row_start, blocksums, N);
    scan_add_k<<<nb_scan, 256, 0, stream>>>(row_start, cursor, blocksums, N, nb_scan);
    scatter_payload_k<<<nb_edge, 256, 0, stream>>>(ei, deprel, deparc, cursor,
                                                   xg, bg_in, bg_out, pe, gate, E);

    fused_agg_gemm_k<<<nb_fused, 512, 0, stream>>>(
        xb, wcatT, pe, gate, row_start, counts, b_in, b_out, Sb, out, bnz, N);
}